// Round 1
// baseline (7330.436 us; speedup 1.0000x reference)
//
#include <hip/hip_runtime.h>
#include <hip/hip_bf16.h>
#include <math.h>

#define HW_   65536
#define B_    2
#define Q_    100
#define C_    134
#define T_    20
#define NHUN  100

__device__ inline float softplusf(float x) {
    // stable log(1+exp(x))
    float ax = fabsf(x);
    return fmaxf(x, 0.0f) + log1pf(expf(-ax));
}

// ---------------- K1: lab_sum[b,t] = sum over 256x256 of ml[b,t,2i,2j] ----------------
__global__ void lab_sum_kernel(const float* __restrict__ ml, float* __restrict__ lab_sum) {
    int bt  = blockIdx.x;          // 0..39  (b*T_+t)
    int tid = threadIdx.x;         // 256 threads
    const float* base = ml + (size_t)bt * 512 * 512;
    float acc = 0.f;
    for (int it = 0; it < 256; ++it) {
        acc += base[it * 1024 + 2 * tid];   // row 2*it, col 2*tid
    }
    for (int off = 32; off > 0; off >>= 1) acc += __shfl_down(acc, off);
    __shared__ float sb[4];
    int wid = tid >> 6, lane = tid & 63;
    if (lane == 0) sb[wid] = acc;
    __syncthreads();
    if (tid == 0) lab_sum[bt] = sb[0] + sb[1] + sb[2] + sb[3];
}

// ---------------- K2: cc[b,q,t] = -softmax(class_logits)[class_labels[b,t]] ----------------
__global__ void class_cost_kernel(const float* __restrict__ cl, const int* __restrict__ labels,
                                  float* __restrict__ cc) {
    int bq  = blockIdx.x;          // 0..199
    int b   = bq / Q_;
    int tid = threadIdx.x;         // 64 threads (one wave)
    __shared__ float sl[C_];
    const float* src = cl + (size_t)bq * C_;
    for (int c = tid; c < C_; c += 64) sl[c] = src[c];
    __syncthreads();
    float mx = -INFINITY;
    for (int c = tid; c < C_; c += 64) mx = fmaxf(mx, sl[c]);
    for (int off = 32; off > 0; off >>= 1) mx = fmaxf(mx, __shfl_xor(mx, off));
    float se = 0.f;
    for (int c = tid; c < C_; c += 64) se += expf(sl[c] - mx);
    for (int off = 32; off > 0; off >>= 1) se += __shfl_xor(se, off);
    float inv = 1.0f / se;
    if (tid < T_) {
        int lbl = labels[b * T_ + tid];
        cc[bq * T_ + tid] = -expf(sl[lbl] - mx) * inv;
    }
}

// ---------------- K3: full cost[b,q,t] ----------------
__global__ __launch_bounds__(1024) void mask_cost_kernel(
        const float* __restrict__ mq, const float* __restrict__ ml,
        const float* __restrict__ cc, const float* __restrict__ lab_sum,
        float* __restrict__ cost) {
    int bq  = blockIdx.x;          // 0..199
    int b   = bq / Q_;
    int tid = threadIdx.x;         // 1024 threads
    const float* xb  = mq + (size_t)bq * HW_;
    const float* mlb = ml + (size_t)b * T_ * 512 * 512;
    float s1[T_], s2[T_];
#pragma unroll
    for (int t = 0; t < T_; ++t) { s1[t] = 0.f; s2[t] = 0.f; }
    float F = 0.f, P = 0.f;
    for (int k = tid; k < HW_; k += 1024) {
        int i = k >> 8, j = k & 255;
        float x = xb[k];
        float p = 1.0f / (1.0f + expf(-x));
        float spn = softplusf(-x);
        float spp = softplusf(x);
        float om = 1.0f - p;
        float fp = 0.25f * om * om * spn;
        float fn = 0.75f * p * p * spp;
        F += fn; P += p;
        float diff = fp - fn;
        int off0 = i * 1024 + 2 * j;   // nearest-resize source offset within (b,t) plane
#pragma unroll
        for (int t = 0; t < T_; ++t) {
            float lab = mlb[t * 262144 + off0];
            s1[t] = fmaf(diff, lab, s1[t]);
            s2[t] = fmaf(p,    lab, s2[t]);
        }
    }
    // deterministic reduction: wave shfl then cross-wave via LDS
    __shared__ float sbuf[16][42];
    int wid = tid >> 6, lane = tid & 63;
#pragma unroll
    for (int t = 0; t < T_; ++t) {
        for (int off = 32; off > 0; off >>= 1) {
            s1[t] += __shfl_down(s1[t], off);
            s2[t] += __shfl_down(s2[t], off);
        }
    }
    for (int off = 32; off > 0; off >>= 1) { F += __shfl_down(F, off); P += __shfl_down(P, off); }
    if (lane == 0) {
#pragma unroll
        for (int t = 0; t < T_; ++t) { sbuf[wid][t] = s1[t]; sbuf[wid][T_ + t] = s2[t]; }
        sbuf[wid][40] = F; sbuf[wid][41] = P;
    }
    __syncthreads();
    if (tid < T_) {
        float S1 = 0.f, S2 = 0.f, Fs = 0.f, Ps = 0.f;
        for (int w = 0; w < 16; ++w) {
            S1 += sbuf[w][tid]; S2 += sbuf[w][T_ + tid];
            Fs += sbuf[w][40];  Ps += sbuf[w][41];
        }
        float L  = lab_sum[b * T_ + tid];
        float cm = (S1 + Fs) * (1.0f / (float)HW_);
        float cd = 1.0f - (2.0f * S2 + 1.0f) / (Ps + L + 1.0f);
        cost[bq * T_ + tid] = cm + cd + cc[bq * T_ + tid];
    }
}

// ---------------- K4: exact JV Hungarian per batch (double, matches reference) ----------------
__global__ void hungarian_kernel(const float* __restrict__ cost, int* __restrict__ out) {
    int b   = blockIdx.x;          // 0..1
    int tid = threadIdx.x;         // 128 threads
    const int n = NHUN;            // 100 (square, zero-padded cols 21..100)
    __shared__ double a[Q_][T_];
    __shared__ double u[NHUN + 1], v[NHUN + 1], minv[NHUN + 1];
    __shared__ int    p[NHUN + 1], way[NHUN + 1];
    __shared__ unsigned char used[NHUN + 1];
    __shared__ int sh_j0;
    __shared__ double rv[128];
    __shared__ int    rj[128];

    for (int idx = tid; idx < Q_ * T_; idx += 128)
        a[idx / T_][idx % T_] = (double)cost[b * Q_ * T_ + idx];
    for (int j = tid; j <= n; j += 128) { u[j] = 0.0; v[j] = 0.0; p[j] = 0; way[j] = 0; }
    __syncthreads();

    for (int i = 1; i <= n; ++i) {
        if (tid == 0) { p[0] = i; sh_j0 = 0; }
        for (int j = tid; j <= n; j += 128) { minv[j] = INFINITY; used[j] = 0; }
        __syncthreads();
        while (true) {
            int j0 = sh_j0;
            if (tid == 0) used[j0] = 1;
            __syncthreads();
            int i0 = p[j0];
            double ui0 = u[i0];
            double myval = INFINITY; int myj = 0x7fffffff;
            if (tid >= 1 && tid <= n && !used[tid]) {
                double aij = (tid <= T_) ? a[i0 - 1][tid - 1] : 0.0;
                double cur = aij - ui0 - v[tid];
                if (cur < minv[tid]) { minv[tid] = cur; way[tid] = j0; }
                myval = minv[tid]; myj = tid;
            }
            rv[tid] = myval; rj[tid] = myj;
            __syncthreads();
            // argmin with first-index tie-break (matches np.argmin)
            for (int s = 64; s > 0; s >>= 1) {
                if (tid < s) {
                    double ov = rv[tid + s]; int oj = rj[tid + s];
                    if (ov < rv[tid] || (ov == rv[tid] && oj < rj[tid])) { rv[tid] = ov; rj[tid] = oj; }
                }
                __syncthreads();
            }
            int j1 = rj[0]; double delta = rv[0];
            if (tid <= n) {
                if (used[tid]) { u[p[tid]] += delta; v[tid] -= delta; }
                else if (tid >= 1) minv[tid] -= delta;
            }
            if (tid == 0) sh_j0 = j1;
            __syncthreads();
            if (p[j1] == 0) break;
        }
        if (tid == 0) {
            int j0 = sh_j0;
            while (j0) { int j1 = way[j0]; p[j0] = p[j1]; j0 = j1; }
        }
        __syncthreads();
    }

    if (tid == 0) {
        int rows[T_], cols[T_];
        for (int j = 1; j <= T_; ++j) { rows[j - 1] = p[j] - 1; cols[j - 1] = j - 1; }
        // insertion sort by row ascending (reference emits ascending-row order)
        for (int s = 1; s < T_; ++s) {
            int r = rows[s], c = cols[s];
            int k = s - 1;
            while (k >= 0 && rows[k] > r) { rows[k + 1] = rows[k]; cols[k + 1] = cols[k]; --k; }
            rows[k + 1] = r; cols[k + 1] = c;
        }
        for (int k = 0; k < T_; ++k) {
            out[b * 2 * T_ + k]      = rows[k];
            out[b * 2 * T_ + T_ + k] = cols[k];
        }
    }
}

extern "C" void kernel_launch(void* const* d_in, const int* in_sizes, int n_in,
                              void* d_out, int out_size, void* d_ws, size_t ws_size,
                              hipStream_t stream) {
    const float* mq     = (const float*)d_in[0];   // [2,100,256,256]
    const float* cl     = (const float*)d_in[1];   // [2,100,134]
    const float* ml     = (const float*)d_in[2];   // [2,20,512,512]
    const int*   labels = (const int*)d_in[3];     // [2,20]
    int* out = (int*)d_out;                        // [2,2,20] int32
    float* ws = (float*)d_ws;
    float* lab_sum = ws;               // 40 floats
    float* cc      = ws + 64;          // 4000 floats
    float* cost    = ws + 64 + 4096;   // 4000 floats

    hipLaunchKernelGGL(lab_sum_kernel,   dim3(B_ * T_), dim3(256),  0, stream, ml, lab_sum);
    hipLaunchKernelGGL(class_cost_kernel,dim3(B_ * Q_), dim3(64),   0, stream, cl, labels, cc);
    hipLaunchKernelGGL(mask_cost_kernel, dim3(B_ * Q_), dim3(1024), 0, stream, mq, ml, cc, lab_sum, cost);
    hipLaunchKernelGGL(hungarian_kernel, dim3(B_),      dim3(128),  0, stream, cost, out);
}

// Round 2
// 209.451 us; speedup vs baseline: 34.9983x; 34.9983x over previous
//
#include <hip/hip_runtime.h>
#include <hip/hip_bf16.h>
#include <math.h>

#define HW_   65536
#define B_    2
#define Q_    100
#define C_    134
#define T_    20
#define NHUN  100

__device__ inline float softplusf(float x) {
    // stable log(1+exp(x))
    float ax = fabsf(x);
    return fmaxf(x, 0.0f) + log1pf(expf(-ax));
}

// ---------------- K1: lab_sum[b,t] = sum over 256x256 of ml[b,t,2i,2j] ----------------
__global__ void lab_sum_kernel(const float* __restrict__ ml, float* __restrict__ lab_sum) {
    int bt  = blockIdx.x;          // 0..39  (b*T_+t)
    int tid = threadIdx.x;         // 256 threads
    const float* base = ml + (size_t)bt * 512 * 512;
    float acc = 0.f;
    for (int it = 0; it < 256; ++it) {
        acc += base[it * 1024 + 2 * tid];   // row 2*it, col 2*tid
    }
    for (int off = 32; off > 0; off >>= 1) acc += __shfl_down(acc, off);
    __shared__ float sb[4];
    int wid = tid >> 6, lane = tid & 63;
    if (lane == 0) sb[wid] = acc;
    __syncthreads();
    if (tid == 0) lab_sum[bt] = sb[0] + sb[1] + sb[2] + sb[3];
}

// ---------------- K2: cc[b,q,t] = -softmax(class_logits)[class_labels[b,t]] ----------------
__global__ void class_cost_kernel(const float* __restrict__ cl, const int* __restrict__ labels,
                                  float* __restrict__ cc) {
    int bq  = blockIdx.x;          // 0..199
    int b   = bq / Q_;
    int tid = threadIdx.x;         // 64 threads (one wave)
    __shared__ float sl[C_];
    const float* src = cl + (size_t)bq * C_;
    for (int c = tid; c < C_; c += 64) sl[c] = src[c];
    __syncthreads();
    float mx = -INFINITY;
    for (int c = tid; c < C_; c += 64) mx = fmaxf(mx, sl[c]);
    for (int off = 32; off > 0; off >>= 1) mx = fmaxf(mx, __shfl_xor(mx, off));
    float se = 0.f;
    for (int c = tid; c < C_; c += 64) se += expf(sl[c] - mx);
    for (int off = 32; off > 0; off >>= 1) se += __shfl_xor(se, off);
    float inv = 1.0f / se;
    if (tid < T_) {
        int lbl = labels[b * T_ + tid];
        cc[bq * T_ + tid] = -expf(sl[lbl] - mx) * inv;
    }
}

// ---------------- K3: full cost[b,q,t] ----------------
__global__ __launch_bounds__(1024) void mask_cost_kernel(
        const float* __restrict__ mq, const float* __restrict__ ml,
        const float* __restrict__ cc, const float* __restrict__ lab_sum,
        float* __restrict__ cost) {
    int bq  = blockIdx.x;          // 0..199
    int b   = bq / Q_;
    int tid = threadIdx.x;         // 1024 threads
    const float* xb  = mq + (size_t)bq * HW_;
    const float* mlb = ml + (size_t)b * T_ * 512 * 512;
    float s1[T_], s2[T_];
#pragma unroll
    for (int t = 0; t < T_; ++t) { s1[t] = 0.f; s2[t] = 0.f; }
    float F = 0.f, P = 0.f;
    for (int k = tid; k < HW_; k += 1024) {
        int i = k >> 8, j = k & 255;
        float x = xb[k];
        float p = 1.0f / (1.0f + expf(-x));
        float spn = softplusf(-x);
        float spp = softplusf(x);
        float om = 1.0f - p;
        float fp = 0.25f * om * om * spn;
        float fn = 0.75f * p * p * spp;
        F += fn; P += p;
        float diff = fp - fn;
        int off0 = i * 1024 + 2 * j;   // nearest-resize source offset within (b,t) plane
#pragma unroll
        for (int t = 0; t < T_; ++t) {
            float lab = mlb[t * 262144 + off0];
            s1[t] = fmaf(diff, lab, s1[t]);
            s2[t] = fmaf(p,    lab, s2[t]);
        }
    }
    // deterministic reduction: wave shfl then cross-wave via LDS
    __shared__ float sbuf[16][42];
    int wid = tid >> 6, lane = tid & 63;
#pragma unroll
    for (int t = 0; t < T_; ++t) {
        for (int off = 32; off > 0; off >>= 1) {
            s1[t] += __shfl_down(s1[t], off);
            s2[t] += __shfl_down(s2[t], off);
        }
    }
    for (int off = 32; off > 0; off >>= 1) { F += __shfl_down(F, off); P += __shfl_down(P, off); }
    if (lane == 0) {
#pragma unroll
        for (int t = 0; t < T_; ++t) { sbuf[wid][t] = s1[t]; sbuf[wid][T_ + t] = s2[t]; }
        sbuf[wid][40] = F; sbuf[wid][41] = P;
    }
    __syncthreads();
    if (tid < T_) {
        float S1 = 0.f, S2 = 0.f, Fs = 0.f, Ps = 0.f;
        for (int w = 0; w < 16; ++w) {
            S1 += sbuf[w][tid]; S2 += sbuf[w][T_ + tid];
            Fs += sbuf[w][40];  Ps += sbuf[w][41];
        }
        float L  = lab_sum[b * T_ + tid];
        float cm = (S1 + Fs) * (1.0f / (float)HW_);
        float cd = 1.0f - (2.0f * S2 + 1.0f) / (Ps + L + 1.0f);
        cost[bq * T_ + tid] = cm + cd + cc[bq * T_ + tid];
    }
}

// ---------------- K4: transposed rectangular JV Hungarian (20 rows x 100 cols), one wave ----------------
// Solves the 20x100 LAP (rows = real target cols, cols = queries). The reference's
// zero-padded 100x100 square solve yields exactly the rectangular optimum on the
// real columns (dummy cols are all-zero), so the assignment sets are identical.
__global__ __launch_bounds__(64) void hungarian_kernel(const float* __restrict__ cost,
                                                       int* __restrict__ out) {
    int b    = blockIdx.x;      // 0..1
    int lane = threadIdx.x;     // 64 threads = 1 wave

    __shared__ float  csh[Q_ * T_];       // cost[q][t] as float
    __shared__ double u[T_ + 1];          // row potentials (rows 1..20)
    __shared__ int    p[NHUN + 1];        // p[j] = row assigned to column j (0 = none)
    __shared__ int    way[NHUN + 1];

    for (int idx = lane; idx < Q_ * T_; idx += 64) csh[idx] = cost[b * Q_ * T_ + idx];
    for (int j = lane; j <= NHUN; j += 64) { p[j] = 0; way[j] = 0; }
    if (lane <= T_) u[lane] = 0.0;
    __syncthreads();

    const int ja = lane;            // owned column A (0..63; 0 is the virtual root)
    const int jb = lane + 64;       // owned column B (64..127)
    const bool jb_ok = (jb <= NHUN);
    double v_a = 0.0, v_b = 0.0;    // column potentials (persist across phases)

    for (int i = 1; i <= T_; ++i) {
        if (lane == 0) p[0] = i;
        double m_a = INFINITY, m_b = INFINITY;
        bool us_a = false, us_b = false;
        __syncthreads();
        int j0 = 0;
        while (true) {
            if (ja == j0) us_a = true;
            if (jb == j0) us_b = true;
            int    i0  = p[j0];
            double ui0 = u[i0];
            // scan owned free columns, update minv/way, form argmin candidate
            double cand = INFINITY; int candj = 0x7fffffff;
            if (!us_a && ja >= 1) {
                double cur = (double)csh[(ja - 1) * T_ + (i0 - 1)] - ui0 - v_a;
                if (cur < m_a) { m_a = cur; way[ja] = j0; }
                cand = m_a; candj = ja;
            }
            if (jb_ok && !us_b) {
                double cur = (double)csh[(jb - 1) * T_ + (i0 - 1)] - ui0 - v_b;
                if (cur < m_b) { m_b = cur; way[jb] = j0; }
                if (m_b < cand || (m_b == cand && jb < candj)) { cand = m_b; candj = jb; }
            }
            // wave argmin (value, then smallest index — matches np.argmin)
            for (int off = 32; off > 0; off >>= 1) {
                double ov = __shfl_xor(cand, off);
                int    oj = __shfl_xor(candj, off);
                if (ov < cand || (ov == cand && oj < candj)) { cand = ov; candj = oj; }
            }
            double delta = cand; int j1 = candj;
            // potential / minv updates (distinct LDS addresses per lane)
            if (us_a) { u[p[ja]] += delta; v_a -= delta; } else { m_a -= delta; }
            if (jb_ok) {
                if (us_b) { u[p[jb]] += delta; v_b -= delta; } else { m_b -= delta; }
            }
            j0 = j1;
            __syncthreads();            // u writes visible before next iteration's read
            if (p[j0] == 0) break;
        }
        // augment: backtrack the alternating path (serial, lane 0)
        if (lane == 0) {
            int jj = j0;
            while (jj) { int jn = way[jj]; p[jj] = p[jn]; jj = jn; }
        }
        __syncthreads();
    }

    if (lane == 0) {
        int* ob = out + b * 2 * T_;
        int k = 0;
        for (int j = 1; j <= NHUN; ++j) {
            if (p[j] != 0) { ob[k] = j - 1; ob[T_ + k] = p[j] - 1; ++k; }  // ascending rows
        }
    }
}

extern "C" void kernel_launch(void* const* d_in, const int* in_sizes, int n_in,
                              void* d_out, int out_size, void* d_ws, size_t ws_size,
                              hipStream_t stream) {
    const float* mq     = (const float*)d_in[0];   // [2,100,256,256]
    const float* cl     = (const float*)d_in[1];   // [2,100,134]
    const float* ml     = (const float*)d_in[2];   // [2,20,512,512]
    const int*   labels = (const int*)d_in[3];     // [2,20]
    int* out = (int*)d_out;                        // [2,2,20] int32
    float* ws = (float*)d_ws;
    float* lab_sum = ws;               // 40 floats
    float* cc      = ws + 64;          // 4000 floats
    float* cost    = ws + 64 + 4096;   // 4000 floats

    hipLaunchKernelGGL(lab_sum_kernel,   dim3(B_ * T_), dim3(256),  0, stream, ml, lab_sum);
    hipLaunchKernelGGL(class_cost_kernel,dim3(B_ * Q_), dim3(64),   0, stream, cl, labels, cc);
    hipLaunchKernelGGL(mask_cost_kernel, dim3(B_ * Q_), dim3(1024), 0, stream, mq, ml, cc, lab_sum, cost);
    hipLaunchKernelGGL(hungarian_kernel, dim3(B_),      dim3(64),   0, stream, cost, out);
}

// Round 3
// 121.266 us; speedup vs baseline: 60.4494x; 1.7272x over previous
//
#include <hip/hip_runtime.h>
#include <hip/hip_bf16.h>
#include <math.h>

#define HW_   65536
#define B_    2
#define Q_    100
#define C_    134
#define T_    20
#define NHUN  100
#define S_    16
#define CHUNK (HW_ / S_)      // 4096 elements per slice
#define NPART 48              // padded partial record (42 used)

// ws layout (floats):
//   LABPS_OFF  = 0        : lab partial sums [40][8]
//   CC_OFF     = 320      : class cost [200][20]
//   COST_OFF   = 4320     : final cost [200][20]
//   tier1: LAB256_OFF = 8320 (2,621,440) ; PART_OFF = 2,629,760 (3200*48)
//   tier2: PART_OFF = 8320
#define LABPS_OFF  0
#define CC_OFF     320
#define COST_OFF   4320
#define BASE_END   8320
#define LAB256_OFF 8320
#define PART1_OFF  (LAB256_OFF + B_ * T_ * HW_)          // 2629760
#define T1_END     (PART1_OFF + S_ * B_ * Q_ * NPART)    // floats
#define PART2_OFF  BASE_END
#define T2_END     (PART2_OFF + S_ * B_ * Q_ * NPART)

__device__ inline float softplusf(float x) {
    float ax = fabsf(x);
    return fmaxf(x, 0.0f) + log1pf(expf(-ax));
}

// ---------------- K1: decimate mask_labels + partial sums ----------------
// grid (bt, 8 row-slices): lab_ps[bt*8+sl] = sum of 32 decimated rows; optionally
// writes compact lab256[bt][r*256+c] = ml[bt][2r*512 + 2c].
__global__ void lab_prep_kernel(const float* __restrict__ ml, float* __restrict__ lab_ps,
                                float* __restrict__ lab256, int compact) {
    int bt  = blockIdx.x;          // 0..39
    int sl  = blockIdx.y;          // 0..7
    int tid = threadIdx.x;         // 256
    const float* base = ml + (size_t)bt * 262144;
    float* dst = lab256 + (size_t)bt * HW_;
    float acc = 0.f;
    for (int r2 = 0; r2 < 32; ++r2) {
        int r = sl * 32 + r2;
        float v = base[r * 1024 + 2 * tid];
        if (compact) dst[r * 256 + tid] = v;
        acc += v;
    }
    for (int off = 32; off > 0; off >>= 1) acc += __shfl_down(acc, off);
    __shared__ float sb[4];
    int wid = tid >> 6, lane = tid & 63;
    if (lane == 0) sb[wid] = acc;
    __syncthreads();
    if (tid == 0) lab_ps[bt * 8 + sl] = sb[0] + sb[1] + sb[2] + sb[3];
}

// ---------------- K2: cc[b,q,t] = -softmax(class_logits)[class_labels[b,t]] ----------------
__global__ void class_cost_kernel(const float* __restrict__ cl, const int* __restrict__ labels,
                                  float* __restrict__ cc) {
    int bq  = blockIdx.x;          // 0..199
    int b   = bq / Q_;
    int tid = threadIdx.x;         // 64
    __shared__ float sl[C_];
    const float* src = cl + (size_t)bq * C_;
    for (int c = tid; c < C_; c += 64) sl[c] = src[c];
    __syncthreads();
    float mx = -INFINITY;
    for (int c = tid; c < C_; c += 64) mx = fmaxf(mx, sl[c]);
    for (int off = 32; off > 0; off >>= 1) mx = fmaxf(mx, __shfl_xor(mx, off));
    float se = 0.f;
    for (int c = tid; c < C_; c += 64) se += expf(sl[c] - mx);
    for (int off = 32; off > 0; off >>= 1) se += __shfl_xor(se, off);
    float inv = 1.0f / se;
    if (tid < T_) {
        int lbl = labels[b * T_ + tid];
        cc[bq * T_ + tid] = -expf(sl[lbl] - mx) * inv;
    }
}

// ---------------- K3: sliced focal/dice partial sums ----------------
// blockIdx.x = s*(B*Q) + bq  (q fastest -> concurrent blocks share lab slice in L2)
template<bool COMPACT>
__global__ __launch_bounds__(256, 4) void focal_kernel(
        const float* __restrict__ mq, const float* __restrict__ lab,
        float* __restrict__ part) {
    int idx = blockIdx.x;
    int s   = idx / (B_ * Q_);
    int bq  = idx % (B_ * Q_);
    int b   = bq / Q_;
    int tid = threadIdx.x;         // 256

    const float* xb = mq + (size_t)bq * HW_ + s * CHUNK;
    const float* labb = COMPACT ? (lab + (size_t)b * T_ * HW_ + s * CHUNK)
                                : (lab + (size_t)b * T_ * 262144);

    float s1[T_], s2[T_];
#pragma unroll
    for (int t = 0; t < T_; ++t) { s1[t] = 0.f; s2[t] = 0.f; }
    float F = 0.f, P = 0.f;

    for (int it = 0; it < CHUNK / 1024; ++it) {     // 4 iterations
        int e4 = it * 256 + tid;                    // float4 index within chunk
        float4 x4 = ((const float4*)xb)[e4];
        float pv[4], dv[4];
#pragma unroll
        for (int e = 0; e < 4; ++e) {
            float x  = (&x4.x)[e];
            float ax = fabsf(x);
            float a  = __expf(-ax);                 // e^{-|x|}
            float r  = 1.0f / (1.0f + a);
            float p  = (x >= 0.f) ? r : a * r;      // sigmoid(x)
            float om = (x >= 0.f) ? a * r : r;      // 1-p
            float l1 = __logf(1.0f + a);            // log1p(e^{-|x|})
            float spn = fmaxf(-x, 0.f) + l1;        // softplus(-x)
            float spp = spn + x;                    // softplus(x)
            float fp = 0.25f * om * om * spn;
            float fn = 0.75f * p * p * spp;
            pv[e] = p; dv[e] = fp - fn;
            F += fn; P += p;
        }
        if (COMPACT) {
#pragma unroll
            for (int t = 0; t < T_; ++t) {
                float4 l4 = ((const float4*)(labb + (size_t)t * HW_))[e4];
                float a1 = s1[t], a2 = s2[t];
                a1 = fmaf(dv[0], l4.x, a1); a2 = fmaf(pv[0], l4.x, a2);
                a1 = fmaf(dv[1], l4.y, a1); a2 = fmaf(pv[1], l4.y, a2);
                a1 = fmaf(dv[2], l4.z, a1); a2 = fmaf(pv[2], l4.z, a2);
                a1 = fmaf(dv[3], l4.w, a1); a2 = fmaf(pv[3], l4.w, a2);
                s1[t] = a1; s2[t] = a2;
            }
        } else {
            int k  = s * CHUNK + e4 * 4;
            int r_ = k >> 8, c_ = k & 255;
            int off = r_ * 1024 + 2 * c_;
#pragma unroll
            for (int t = 0; t < T_; ++t) {
                const float* pl = labb + (size_t)t * 262144 + off;
                float a1 = s1[t], a2 = s2[t];
                a1 = fmaf(dv[0], pl[0], a1); a2 = fmaf(pv[0], pl[0], a2);
                a1 = fmaf(dv[1], pl[2], a1); a2 = fmaf(pv[1], pl[2], a2);
                a1 = fmaf(dv[2], pl[4], a1); a2 = fmaf(pv[2], pl[4], a2);
                a1 = fmaf(dv[3], pl[6], a1); a2 = fmaf(pv[3], pl[6], a2);
                s1[t] = a1; s2[t] = a2;
            }
        }
    }

    // deterministic reduction: wave shfl, then cross-wave LDS
    __shared__ float sbuf[4][NPART];
    int wid = tid >> 6, lane = tid & 63;
#pragma unroll
    for (int t = 0; t < T_; ++t) {
        for (int off = 32; off > 0; off >>= 1) {
            s1[t] += __shfl_down(s1[t], off);
            s2[t] += __shfl_down(s2[t], off);
        }
    }
    for (int off = 32; off > 0; off >>= 1) { F += __shfl_down(F, off); P += __shfl_down(P, off); }
    if (lane == 0) {
#pragma unroll
        for (int t = 0; t < T_; ++t) { sbuf[wid][t] = s1[t]; sbuf[wid][T_ + t] = s2[t]; }
        sbuf[wid][40] = F; sbuf[wid][41] = P;
    }
    __syncthreads();
    if (tid < 42) {
        float v = sbuf[0][tid] + sbuf[1][tid] + sbuf[2][tid] + sbuf[3][tid];
        part[(size_t)idx * NPART + tid] = v;
    }
}

// ---------------- K4: compose final cost ----------------
__global__ void compose_kernel(const float* __restrict__ part, const float* __restrict__ cc,
                               const float* __restrict__ lab_ps, float* __restrict__ cost) {
    int bq   = blockIdx.x;         // 0..199
    int b    = bq / Q_;
    int lane = threadIdx.x;        // 64
    if (lane < T_) {
        float S1 = 0.f, S2 = 0.f, F = 0.f, P = 0.f;
        for (int s = 0; s < S_; ++s) {
            const float* pp = part + ((size_t)s * (B_ * Q_) + bq) * NPART;
            S1 += pp[lane]; S2 += pp[T_ + lane]; F += pp[40]; P += pp[41];
        }
        float L = 0.f;
        for (int sl = 0; sl < 8; ++sl) L += lab_ps[(b * T_ + lane) * 8 + sl];
        float cm = (S1 + F) * (1.0f / (float)HW_);
        float cd = 1.0f - (2.0f * S2 + 1.0f) / (P + L + 1.0f);
        cost[bq * T_ + lane] = cm + cd + cc[bq * T_ + lane];
    }
}

// ---------------- tier-3 fallback: monolithic (round-2 proven) ----------------
__global__ __launch_bounds__(1024) void mask_cost_mono_kernel(
        const float* __restrict__ mq, const float* __restrict__ ml,
        const float* __restrict__ cc, const float* __restrict__ lab_ps,
        float* __restrict__ cost) {
    int bq  = blockIdx.x;
    int b   = bq / Q_;
    int tid = threadIdx.x;
    const float* xb  = mq + (size_t)bq * HW_;
    const float* mlb = ml + (size_t)b * T_ * 262144;
    float s1[T_], s2[T_];
#pragma unroll
    for (int t = 0; t < T_; ++t) { s1[t] = 0.f; s2[t] = 0.f; }
    float F = 0.f, P = 0.f;
    for (int k = tid; k < HW_; k += 1024) {
        int i = k >> 8, j = k & 255;
        float x = xb[k];
        float p = 1.0f / (1.0f + expf(-x));
        float spn = softplusf(-x);
        float spp = softplusf(x);
        float om = 1.0f - p;
        float fp = 0.25f * om * om * spn;
        float fn = 0.75f * p * p * spp;
        F += fn; P += p;
        float diff = fp - fn;
        int off0 = i * 1024 + 2 * j;
#pragma unroll
        for (int t = 0; t < T_; ++t) {
            float lab = mlb[t * 262144 + off0];
            s1[t] = fmaf(diff, lab, s1[t]);
            s2[t] = fmaf(p,    lab, s2[t]);
        }
    }
    __shared__ float sbuf[16][42];
    int wid = tid >> 6, lane = tid & 63;
#pragma unroll
    for (int t = 0; t < T_; ++t) {
        for (int off = 32; off > 0; off >>= 1) {
            s1[t] += __shfl_down(s1[t], off);
            s2[t] += __shfl_down(s2[t], off);
        }
    }
    for (int off = 32; off > 0; off >>= 1) { F += __shfl_down(F, off); P += __shfl_down(P, off); }
    if (lane == 0) {
#pragma unroll
        for (int t = 0; t < T_; ++t) { sbuf[wid][t] = s1[t]; sbuf[wid][T_ + t] = s2[t]; }
        sbuf[wid][40] = F; sbuf[wid][41] = P;
    }
    __syncthreads();
    if (tid < T_) {
        float S1 = 0.f, S2 = 0.f, Fs = 0.f, Ps = 0.f;
        for (int w = 0; w < 16; ++w) {
            S1 += sbuf[w][tid]; S2 += sbuf[w][T_ + tid];
            Fs += sbuf[w][40];  Ps += sbuf[w][41];
        }
        float L = 0.f;
        for (int sl = 0; sl < 8; ++sl) L += lab_ps[(b * T_ + tid) * 8 + sl];
        float cm = (S1 + Fs) * (1.0f / (float)HW_);
        float cd = 1.0f - (2.0f * S2 + 1.0f) / (Ps + L + 1.0f);
        cost[bq * T_ + tid] = cm + cd + cc[bq * T_ + tid];
    }
}

// ---------------- K5: transposed rectangular JV Hungarian, one wave ----------------
__global__ __launch_bounds__(64) void hungarian_kernel(const float* __restrict__ cost,
                                                       int* __restrict__ out) {
    int b    = blockIdx.x;
    int lane = threadIdx.x;

    __shared__ float  csh[Q_ * T_];
    __shared__ double u[T_ + 1];
    __shared__ int    p[NHUN + 1];
    __shared__ int    way[NHUN + 1];

    for (int idx = lane; idx < Q_ * T_; idx += 64) csh[idx] = cost[b * Q_ * T_ + idx];
    for (int j = lane; j <= NHUN; j += 64) { p[j] = 0; way[j] = 0; }
    if (lane <= T_) u[lane] = 0.0;
    __syncthreads();

    const int ja = lane;
    const int jb = lane + 64;
    const bool jb_ok = (jb <= NHUN);
    double v_a = 0.0, v_b = 0.0;

    for (int i = 1; i <= T_; ++i) {
        if (lane == 0) p[0] = i;
        double m_a = INFINITY, m_b = INFINITY;
        bool us_a = false, us_b = false;
        __syncthreads();
        int j0 = 0;
        while (true) {
            if (ja == j0) us_a = true;
            if (jb == j0) us_b = true;
            int    i0  = p[j0];
            double ui0 = u[i0];
            double cand = INFINITY; int candj = 0x7fffffff;
            if (!us_a && ja >= 1) {
                double cur = (double)csh[(ja - 1) * T_ + (i0 - 1)] - ui0 - v_a;
                if (cur < m_a) { m_a = cur; way[ja] = j0; }
                cand = m_a; candj = ja;
            }
            if (jb_ok && !us_b) {
                double cur = (double)csh[(jb - 1) * T_ + (i0 - 1)] - ui0 - v_b;
                if (cur < m_b) { m_b = cur; way[jb] = j0; }
                if (m_b < cand || (m_b == cand && jb < candj)) { cand = m_b; candj = jb; }
            }
            for (int off = 32; off > 0; off >>= 1) {
                double ov = __shfl_xor(cand, off);
                int    oj = __shfl_xor(candj, off);
                if (ov < cand || (ov == cand && oj < candj)) { cand = ov; candj = oj; }
            }
            double delta = cand; int j1 = candj;
            if (us_a) { u[p[ja]] += delta; v_a -= delta; } else { m_a -= delta; }
            if (jb_ok) {
                if (us_b) { u[p[jb]] += delta; v_b -= delta; } else { m_b -= delta; }
            }
            j0 = j1;
            __syncthreads();
            if (p[j0] == 0) break;
        }
        if (lane == 0) {
            int jj = j0;
            while (jj) { int jn = way[jj]; p[jj] = p[jn]; jj = jn; }
        }
        __syncthreads();
    }

    if (lane == 0) {
        int* ob = out + b * 2 * T_;
        int k = 0;
        for (int j = 1; j <= NHUN; ++j) {
            if (p[j] != 0) { ob[k] = j - 1; ob[T_ + k] = p[j] - 1; ++k; }
        }
    }
}

extern "C" void kernel_launch(void* const* d_in, const int* in_sizes, int n_in,
                              void* d_out, int out_size, void* d_ws, size_t ws_size,
                              hipStream_t stream) {
    const float* mq     = (const float*)d_in[0];   // [2,100,256,256]
    const float* cl     = (const float*)d_in[1];   // [2,100,134]
    const float* ml     = (const float*)d_in[2];   // [2,20,512,512]
    const int*   labels = (const int*)d_in[3];     // [2,20]
    int* out = (int*)d_out;                        // [2,2,20] int32
    float* ws = (float*)d_ws;

    float* lab_ps = ws + LABPS_OFF;
    float* cc     = ws + CC_OFF;
    float* cost   = ws + COST_OFF;

    size_t need_t1 = (size_t)T1_END * 4;
    size_t need_t2 = (size_t)T2_END * 4;

    if (ws_size >= need_t1) {
        float* lab256 = ws + LAB256_OFF;
        float* part   = ws + PART1_OFF;
        hipLaunchKernelGGL(lab_prep_kernel,   dim3(B_ * T_, 8), dim3(256), 0, stream, ml, lab_ps, lab256, 1);
        hipLaunchKernelGGL(class_cost_kernel, dim3(B_ * Q_),    dim3(64),  0, stream, cl, labels, cc);
        hipLaunchKernelGGL((focal_kernel<true>), dim3(S_ * B_ * Q_), dim3(256), 0, stream, mq, lab256, part);
        hipLaunchKernelGGL(compose_kernel,    dim3(B_ * Q_),    dim3(64),  0, stream, part, cc, lab_ps, cost);
    } else if (ws_size >= need_t2) {
        float* part = ws + PART2_OFF;
        hipLaunchKernelGGL(lab_prep_kernel,   dim3(B_ * T_, 8), dim3(256), 0, stream, ml, lab_ps, ws, 0);
        hipLaunchKernelGGL(class_cost_kernel, dim3(B_ * Q_),    dim3(64),  0, stream, cl, labels, cc);
        hipLaunchKernelGGL((focal_kernel<false>), dim3(S_ * B_ * Q_), dim3(256), 0, stream, mq, ml, part);
        hipLaunchKernelGGL(compose_kernel,    dim3(B_ * Q_),    dim3(64),  0, stream, part, cc, lab_ps, cost);
    } else {
        hipLaunchKernelGGL(lab_prep_kernel,   dim3(B_ * T_, 8), dim3(256), 0, stream, ml, lab_ps, ws, 0);
        hipLaunchKernelGGL(class_cost_kernel, dim3(B_ * Q_),    dim3(64),  0, stream, cl, labels, cc);
        hipLaunchKernelGGL(mask_cost_mono_kernel, dim3(B_ * Q_), dim3(1024), 0, stream, mq, ml, cc, lab_ps, cost);
    }
    hipLaunchKernelGGL(hungarian_kernel, dim3(B_), dim3(64), 0, stream, cost, out);
}